// Round 5
// baseline (225.411 us; speedup 1.0000x reference)
//
#include <hip/hip_runtime.h>

// APoT (8-bit, m=2) quantizer, eval forward — bit-logic, divide-free fast path.
//
// Codebook = {0, ±2^-p, ±(2^-p + 2^-q)}: every level is an fp32 with at most
// TWO mantissa bits set, finest bit 2^-15 absolute. Nearest-level with
// searchsorted/argmin-first tie-break == exact integer logic on the bit
// pattern of |xn| (verified absmax == 0.0 across all rounds).
//
// R4: per-element IEEE divide replaced by q0 = x * (1/alpha) + exact-decision
// margin test; rare lanes (|d|<=8, ~1e-6) redo the true divide under exec
// mask -> bit-exact.
//
// Policy ablation history (kernel dispatch time, 16 elems/thread):
//   nt load + nt store      : 63-71 us  (R4/R7)
//   nt load + cached store  : ~64 us    (R8, within noise of nt/nt)
//   cached load + nt store  : 80 us     (R6)
//   cached load + cached st : 91 us     (R5)
// -> loads nt (worth 10-25 us), stores don't matter. Policy matrix closed.
//
// R9 (this round): GEOMETRY. R5's cached/cached moved 268MB at 2.9 TB/s
// while the m13 float4-copy ubench with identical policy hits 6.29 TB/s —
// policy doesn't explain the gap, shape might. Ubench shape = 1 float4 per
// thread, huge grid. Our 16-elems/thread shape provably serialized per-wave
// (VGPR_Count=16, R5/R6; asm-liveness R7 neutral). With 1 float4/thread the
// intra-wave chain disappears: every wave issues its load at dispatch, and
// wave retire/refill provides the memory pipelining. Grid 8192 -> 32768.
//
// Tie semantics (argmin-first): xn>0 tie -> smaller value; xn<0 -> larger mag.

typedef float vfloat4 __attribute__((ext_vector_type(4)));

__device__ __forceinline__ unsigned apot_pick(unsigned a, unsigned s, int& d) {
    // a = bit pattern of clamped |xn| (<= 0x3F800000). Returns level bits
    // (sign excluded); d = signed distance of 2m from the decision midpoint.
    unsigned q;
    if (a >= 0x38000000u) {               // |xn| >= 2^-15 : ~99.999% of data
        const unsigned e    = a >> 23;          // 112..127
        const unsigned m    = a & 0x7FFFFFu;
        const unsigned base = a - m;            // e<<23
        const unsigned g    = 1u << (135u - e); // finest grid bit (abs 2^-15)
        const unsigned L    = 31u - __clz(m | 1u);
        const unsigned bit  = 1u << L;
        const bool fine = (m < g);
        const unsigned lo  = fine ? base       : (base | bit);
        const unsigned hi  = fine ? (base + g) : (base + (bit << 1));
        const unsigned mid = fine ? g : (bit + (bit << 1));
        d = (int)(m + m) - (int)mid;
        const bool pickLo = (d < 0) | ((d == 0) & (s == 0u));
        q = pickLo ? lo : hi;
    } else {
        // |xn| < 2^-15: neighbors {0, 2^-15}; midpoint 2^-16
        d = (int)a - (int)0x37800000u;
        const bool pickZero = (d < 0) | ((d == 0) & (s == 0u));
        q = pickZero ? 0u : 0x38000000u;
    }
    return q;
}

__device__ __forceinline__ float apot_q1(float xv, float r, float alpha_pos) {
    // fast path: approximate quotient, exact-decision margin test
    const float q0 = xv * r;
    float xn = fminf(1.0f, fmaxf(-1.0f, q0));
    unsigned u = __float_as_uint(xn);
    unsigned s = u & 0x80000000u;
    int d;
    unsigned q = apot_pick(u & 0x7FFFFFFFu, s, d);
    if (d < 9 && d > -9) {
        // within margin of a decision boundary: redo with exact IEEE divide
        const float xe = fminf(1.0f, fmaxf(-1.0f, xv / alpha_pos));
        const unsigned ue = __float_as_uint(xe);
        s = ue & 0x80000000u;
        q = apot_pick(ue & 0x7FFFFFFFu, s, d);
    }
    return __uint_as_float(q | s) * alpha_pos;
}

// Copy-ubench shape: one dwordx4 load, quant, one dwordx4 store per thread.
__global__ __launch_bounds__(256) void apot_quant_kernel(
    const float* __restrict__ x,
    const float* __restrict__ alpha,
    float* __restrict__ out,
    int n)
{
    const float alpha_pos = fabsf(alpha[0]) + 1e-5f;
    const float r = 1.0f / alpha_pos;   // uniform: one divide per thread

    const int i0 = (blockIdx.x * 256 + (int)threadIdx.x) * 4;

    if (i0 + 4 <= n) {
        vfloat4 v = __builtin_nontemporal_load((const vfloat4*)(x + i0));
        vfloat4 o;
        #pragma unroll
        for (int e = 0; e < 4; ++e) o[e] = apot_q1(v[e], r, alpha_pos);
        __builtin_nontemporal_store(o, (vfloat4*)(out + i0));
    } else {
        // generic tail (not hit for 4096x8192: n % 1024 == 0)
        for (int e = 0; e < 4; ++e) {
            const int idx = i0 + e;
            if (idx < n) out[idx] = apot_q1(x[idx], r, alpha_pos);
        }
    }
}

extern "C" void kernel_launch(void* const* d_in, const int* in_sizes, int n_in,
                              void* d_out, int out_size, void* d_ws, size_t ws_size,
                              hipStream_t stream) {
    const float* x     = (const float*)d_in[0];
    const float* alpha = (const float*)d_in[1];
    // d_in[2] (codebook) is implied by the bit logic; not read.
    float* out         = (float*)d_out;

    const int n = in_sizes[0];            // 33,554,432
    const int elemsPerBlock = 256 * 4;
    const int grid = (n + elemsPerBlock - 1) / elemsPerBlock;  // 32768

    apot_quant_kernel<<<grid, 256, 0, stream>>>(x, alpha, out, n);
}

// Round 6
// 223.355 us; speedup vs baseline: 1.0092x; 1.0092x over previous
//
#include <hip/hip_runtime.h>

// APoT (8-bit, m=2) quantizer, eval forward — bit-logic, divide-free fast path.
//
// Codebook = {0, ±2^-p, ±(2^-p + 2^-q)}: every level is an fp32 with at most
// TWO mantissa bits set, finest bit 2^-15 absolute. Nearest-level with
// searchsorted/argmin-first tie-break == exact integer logic on the bit
// pattern of |xn| (verified absmax == 0.0 across all rounds).
//
// Ledger (kernel dispatch time):
//   R4/R7  nt/nt 16 elems/thread        : 63-71 us  (best)
//   R8     nt/cached                    : ~64 us (noise)
//   R6     cached/nt                    : 80 us
//   R5     cached/cached                : 91 us
//   R7     asm-forced MLP=4             : flat
//   R9     1 float4/thread (ubench shape): flat
// Policy matrix, MLP, and geometry all closed. Remaining unexplained number:
// VALUBusy 37% @ 91us (R5) => ~34us VALU-issue time vs ~13us algorithmic
// estimate — compiled path is ~2.5x fat (predicated dual paths, per-element
// exec-mask slow-path machinery, IEEE 1/alpha divide, addr math). With a
// 43us memory floor and 65us wall, un-overlapped VALU is the last standing
// co-limiter theory.
//
// R10 (this round): VALU THINNING, bit-identical semantics.
//   1. apot_pick algebraic rewrite: hi = lo+step, d = 2(m-lom)-step
//      (drops ~5 cndmask/add per element).
//   2. r = v_rcp(alpha_pos) instead of IEEE divide (~10 inst -> 1, per
//      thread). Fast-path decision error grows to <=12 d-units -> margin
//      widened 9 -> 16. Slow path unchanged (exact IEEE divide) => decisions
//      bit-exact by the same edge-consistency argument; all exact ties still
//      fall inside the margin and take the slow path.
//   3. Margin check batched per 4 elems: one branch (OR of 4 range tests)
//      replaces 4 exec-mask save/restore sequences; rare trigger (~1e-5)
//      recomputes all 4 with the exact divide.
// Structure = R0 exactly (16 elems/thread, nt loads, nt stores, no asm).
//
// Tie semantics (argmin-first): ties always -> smaller VALUE
// (s=0 -> lo, s=1 -> hi in magnitude space).

typedef float vfloat4 __attribute__((ext_vector_type(4)));

__device__ __forceinline__ unsigned apot_pick(unsigned a, unsigned s, int& d) {
    // a = bit pattern of clamped |xn| (<= 0x3F800000). Returns level bits
    // (sign excluded); d = signed distance of 2m from the decision midpoint.
    unsigned q;
    if (a >= 0x38000000u) {               // |xn| >= 2^-15 : ~99.999% of data
        const unsigned m    = a & 0x7FFFFFu;
        const unsigned base = a - m;                      // e<<23
        const unsigned g    = 1u << (135u - (a >> 23));   // finest grid bit
        const unsigned bit  = 0x80000000u >> __clz(m | 1u); // leading bit of m
        const bool     fine = (m < g);
        const unsigned step = fine ? g : bit;   // hi - lo
        const unsigned lom  = fine ? 0u : bit;  // lo's mantissa
        const unsigned lo   = base + lom;
        d = (int)((m - lom) << 1) - (int)step;  // == 2m - (2*lom + step)
        const bool pickLo = (d < 0) | ((d == 0) & (s == 0u));
        q = pickLo ? lo : (lo + step);
    } else {
        // |xn| < 2^-15: neighbors {0, 2^-15}; midpoint 2^-16
        d = (int)a - (int)0x37800000u;
        const bool pickZero = (d < 0) | ((d == 0) & (s == 0u));
        q = pickZero ? 0u : 0x38000000u;
    }
    return q;
}

__device__ __forceinline__ unsigned apot_fast(float xv, float r, int& d) {
    const float q0 = xv * r;                       // approx quotient (rcp r)
    const float xn = fminf(1.0f, fmaxf(-1.0f, q0));
    const unsigned u = __float_as_uint(xn);
    const unsigned s = u & 0x80000000u;
    return apot_pick(u & 0x7FFFFFFFu, s, d) | s;
}

__device__ __forceinline__ unsigned apot_exact(float xv, float alpha_pos) {
    int d;
    const float xe = fminf(1.0f, fmaxf(-1.0f, xv / alpha_pos)); // IEEE divide
    const unsigned ue = __float_as_uint(xe);
    const unsigned s = ue & 0x80000000u;
    return apot_pick(ue & 0x7FFFFFFFu, s, d) | s;
}

__device__ __forceinline__ float apot_q1(float xv, float r, float alpha_pos) {
    int d;
    unsigned q = apot_fast(xv, r, d);
    if ((unsigned)(d + 15) < 31u)          // |d| <= 15: near decision boundary
        q = apot_exact(xv, alpha_pos);
    return __uint_as_float(q) * alpha_pos;
}

__device__ __forceinline__ vfloat4 quant4(vfloat4 v, float r, float alpha_pos) {
    int d0, d1, d2, d3;
    unsigned q0 = apot_fast(v[0], r, d0);
    unsigned q1 = apot_fast(v[1], r, d1);
    unsigned q2 = apot_fast(v[2], r, d2);
    unsigned q3 = apot_fast(v[3], r, d3);
    // one branch per 4 elems: any |d| <= 15 -> redo all 4 exactly (rare ~1e-5)
    const bool t0 = (unsigned)(d0 + 15) < 31u;
    const bool t1 = (unsigned)(d1 + 15) < 31u;
    const bool t2 = (unsigned)(d2 + 15) < 31u;
    const bool t3 = (unsigned)(d3 + 15) < 31u;
    if ((t0 | t1) | (t2 | t3)) {
        q0 = apot_exact(v[0], alpha_pos);
        q1 = apot_exact(v[1], alpha_pos);
        q2 = apot_exact(v[2], alpha_pos);
        q3 = apot_exact(v[3], alpha_pos);
    }
    vfloat4 o;
    o[0] = __uint_as_float(q0) * alpha_pos;
    o[1] = __uint_as_float(q1) * alpha_pos;
    o[2] = __uint_as_float(q2) * alpha_pos;
    o[3] = __uint_as_float(q3) * alpha_pos;
    return o;
}

// R0 structure: one-shot blocks, 16 elems/thread, nt loads + nt stores.
__global__ __launch_bounds__(256) void apot_quant_kernel(
    const float* __restrict__ x,
    const float* __restrict__ alpha,
    float* __restrict__ out,
    int n)
{
    const float alpha_pos = fabsf(alpha[0]) + 1e-5f;
    const float r = __builtin_amdgcn_rcpf(alpha_pos);  // 1 inst; margin covers error

    const int blockStart = blockIdx.x * (256 * 16);
    const int i0 = blockStart + (int)threadIdx.x * 4;

    if (blockStart + 256 * 16 <= n) {
        vfloat4 v0 = __builtin_nontemporal_load((const vfloat4*)(x + i0));
        vfloat4 v1 = __builtin_nontemporal_load((const vfloat4*)(x + i0 + 1024));
        vfloat4 v2 = __builtin_nontemporal_load((const vfloat4*)(x + i0 + 2048));
        vfloat4 v3 = __builtin_nontemporal_load((const vfloat4*)(x + i0 + 3072));
        __builtin_nontemporal_store(quant4(v0, r, alpha_pos), (vfloat4*)(out + i0));
        __builtin_nontemporal_store(quant4(v1, r, alpha_pos), (vfloat4*)(out + i0 + 1024));
        __builtin_nontemporal_store(quant4(v2, r, alpha_pos), (vfloat4*)(out + i0 + 2048));
        __builtin_nontemporal_store(quant4(v3, r, alpha_pos), (vfloat4*)(out + i0 + 3072));
    } else {
        // generic tail (not hit for 4096x8192: n % 4096 == 0)
        for (int t = 0; t < 4; ++t) {
            for (int e = 0; e < 4; ++e) {
                const int idx = i0 + t * 1024 + e;
                if (idx < n) out[idx] = apot_q1(x[idx], r, alpha_pos);
            }
        }
    }
}

extern "C" void kernel_launch(void* const* d_in, const int* in_sizes, int n_in,
                              void* d_out, int out_size, void* d_ws, size_t ws_size,
                              hipStream_t stream) {
    const float* x     = (const float*)d_in[0];
    const float* alpha = (const float*)d_in[1];
    // d_in[2] (codebook) is implied by the bit logic; not read.
    float* out         = (float*)d_out;

    const int n = in_sizes[0];            // 33,554,432
    const int elemsPerBlock = 256 * 16;
    const int grid = (n + elemsPerBlock - 1) / elemsPerBlock;  // 8192

    apot_quant_kernel<<<grid, 256, 0, stream>>>(x, alpha, out, n);
}